// Round 2
// 8432.548 us; speedup vs baseline: 1.2472x; 1.2472x over previous
//
#include <hip/hip_runtime.h>
#include <hip/hip_fp8.h>
#include <math.h>

// Problem constants
#define BB 64
#define SS 512
#define EE 256
#define HH 512
#define HD 1024
#define TT 9
#define MM (BB*SS)

typedef __attribute__((ext_vector_type(8))) short    short8;   // 8 bf16
typedef __attribute__((ext_vector_type(4))) float    f32x4;
typedef __attribute__((ext_vector_type(4))) unsigned uint4v;

__device__ __forceinline__ unsigned short f2bfu(float x) {
    unsigned b = __float_as_uint(x);
    b += 0x7FFFu + ((b >> 16) & 1u);      // RNE
    return (unsigned short)(b >> 16);
}
__device__ __forceinline__ unsigned pack2bf(float lo, float hi) {
    return ((unsigned)f2bfu(hi) << 16) | (unsigned)f2bfu(lo);
}

// ---------------------------------------------------------------------------
__global__ void zero_kernel(float* __restrict__ p, int n)
{
    int i = blockIdx.x * blockDim.x + threadIdx.x;
    int stride = gridDim.x * blockDim.x;
    for (; i < n; i += stride) p[i] = 0.f;
}

// ---------------------------------------------------------------------------
// Pack [w_ih | w_hh] fp32 -> MFMA-A-frag-linear bf16, NJ=4 tiles (M=16).
// tid = ((((d*128+jb)*nf + f)*64 + lane)*8 + j
// A row m = lane&15, ordered m = jj*4 + q  (jj = unit 0..3, q = gate i,f,g,o)
// -> each lane's C rows (quad*4+i) give ALL 4 gates of unit jj=quad.
// k = f*32 + (lane>>4)*8 + j;  k<KX -> w_ih else w_hh.
// Tile jb' = ub*4+wv covers units ub*16+wv*4+jj == the wave->unit mapping.
// ---------------------------------------------------------------------------
__global__ void pack_kernel(const float* __restrict__ w_ih, const float* __restrict__ w_hh,
                            unsigned short* __restrict__ dst, int KX, int nf, int total)
{
    int tid = blockIdx.x * 256 + threadIdx.x;
    if (tid >= total) return;
    int j    = tid & 7;
    int lane = (tid >> 3) & 63;
    int f    = (tid >> 9) % nf;
    int rest = (tid >> 9) / nf;
    int jb   = rest & 127;
    int d    = rest >> 7;
    int m = lane & 15, quad = lane >> 4;
    int jj = m >> 2, q = m & 3;
    int row = q * HH + jb * 4 + jj;
    int k   = f * 32 + quad * 8 + j;
    float v;
    if (k < KX) v = w_ih[((size_t)d * 2048 + row) * (size_t)KX + k];
    else        v = w_hh[((size_t)d * 2048 + row) * (size_t)HH + (k - KX)];
    dst[tid] = f2bfu(v);
}

// ---------------------------------------------------------------------------
// Persistent BiLSTM layer — ROUND 8 restructure (round-9 fix: h1out d*HH):
// batch-group sync domains + per-wave distributed flags + h-load/x-MFMA
// overlap.
//
// 256 blocks x 256 threads, 1 block/CU.  bid = d*128 + g*32 + ub:
//   d  = direction, g = batch group (16 batches), ub = unit block (16 units).
// Wave wv owns packA tile jb = ub*4+wv (units jb*4..jb*4+3), batches g*16+ln15.
// The recurrence couples units, NOT batches -> the 8 (d,g) domains are fully
// independent: 128-wave flag barriers per domain, no cross-domain coupling.
//
// Per step (per wave, NO __syncthreads anywhere in the loop):
//  1. issue x loads (ids from LDS for L0; latency hides under poll)
//  2. poll: one u64 load/lane covers all 128 wave-flags, __all reduce
//  3. issue 32 h MALL loads  (latency hides under x-MFMAs)
//  4. x MFMAs   5. h MFMAs   6. epilogue + h stores
//  7. s_waitcnt vmcnt(0) (h stores at MALL)  -> store own flag = s+1
// Skew between waves of a domain is bounded by 1 step -> 2-deep ping-pong of
// hbuf stays race-free: ping s&1 is only overwritten at step s+1, which
// requires all flags >= s+1, which requires every reader's vmcnt(0) drain.
// ---------------------------------------------------------------------------
template<int LAYER>
__global__ __launch_bounds__(256, 1)
void bilstm_persist(const int* __restrict__ ids, const float* __restrict__ emb,
                    const unsigned short* __restrict__ x1,   // L1 input = h0out bf16
                    const unsigned short* __restrict__ packA,
                    const float* __restrict__ b_ih, const float* __restrict__ b_hh,
                    unsigned short* hbuf,                 // [2dir][2ping][64][512] bf16
                    unsigned short* __restrict__ h0out,   // L0 out (bf16)
                    unsigned char*  __restrict__ h1out,   // L1 out (fp8 e4m3)
                    unsigned* flags)                      // 1024 u32: (d*4+g)*128 + jb
{
    constexpr int KX = LAYER ? HD : EE;
    constexpr int NF = (KX + HH) / 32;    // total k-frags (L0 24, L1 48)
    constexpr int XF = KX / 32;           // x frags (8 / 32)
    constexpr int HF = HH / 32;           // 16
    constexpr int XFA = (LAYER == 0) ? XF : 1;
    constexpr int XFB = (LAYER == 1) ? XF : 1;

    __shared__ int sid[16 * 513];         // L0 only: this group's ids, pad 513 (bank-safe)

    const int bid  = blockIdx.x;
    const int d    = bid >> 7;
    const int g    = (bid >> 5) & 3;
    const int ub   = bid & 31;
    const int tid  = threadIdx.x;
    const int lane = tid & 63;
    const int wv   = tid >> 6;
    const int quad = lane >> 4;
    const int ln15 = lane & 15;
    const int b    = g * 16 + ln15;       // this lane's batch
    const int jb   = ub * 4 + wv;         // packA tile / flag index within domain
    const int u    = jb * 4 + quad;       // this lane's hidden unit

    if (LAYER == 0) {
        for (int i = tid; i < 16 * 512; i += 256) {
            int r = i >> 9, cc = i & 511;
            sid[r * 513 + cc] = ids[(g * 16 + r) * SS + cc];
        }
        __syncthreads();                  // once, before the loop
    }

    // ---- A stationary: load whole weight tile into VGPRs once ----
    const uint4v* myA = (const uint4v*)(packA + (size_t)(d * 128 + jb) * NF * 512);
    uint4v Ar[NF];
    #pragma unroll
    for (int f = 0; f < NF; f++) Ar[f] = myA[f * 64 + lane];

    float bias_[4];
    #pragma unroll
    for (int q = 0; q < 4; q++)
        bias_[q] = b_ih[d * 2048 + q * HH + u] + b_hh[d * 2048 + q * HH + u];

    unsigned* gflags = flags + (d * 4 + g) * 128;          // this domain's 128 wave flags
    const unsigned long long* fq = (const unsigned long long*)gflags;

    float c_ = 0.f;

    for (int s = 0; s < SS; s++) {
        const int t = d ? (SS - 1 - s) : s;
        const int p = s & 1;
        f32x4 acc = {0.f, 0.f, 0.f, 0.f};

        // ---- 1. issue x loads (no cross-block dependence; fly under the poll) ----
        float4 Fa[XFA], Fb[XFA];
        uint4v Bx[XFB];
        if constexpr (LAYER == 0) {
            const float* erow = emb + (size_t)sid[ln15 * 513 + t] * EE;
            #pragma unroll
            for (int f = 0; f < XF; f++) {
                const int k0 = f * 32 + quad * 8;
                Fa[f] = *(const float4*)(erow + k0);
                Fb[f] = *(const float4*)(erow + k0 + 4);
            }
        } else {
            const unsigned short* xrow = x1 + ((size_t)(b * SS + t)) * HD;
            #pragma unroll
            for (int f = 0; f < XF; f++)
                Bx[f] = *(const uint4v*)(xrow + f * 32 + quad * 8);
        }
        __builtin_amdgcn_sched_barrier(0);   // pin x-load issue above the poll

        // ---- 2. wait: all 128 waves of this (dir,group) finished step s-1 ----
        if (s) {
            const unsigned tgt = (unsigned)s;
            while (1) {
                unsigned long long q = __hip_atomic_load(fq + lane,
                                         __ATOMIC_RELAXED, __HIP_MEMORY_SCOPE_AGENT);
                if (__all(((unsigned)q >= tgt) & ((unsigned)(q >> 32) >= tgt))) break;
                __builtin_amdgcn_s_sleep(1);
            }
            __atomic_signal_fence(__ATOMIC_ACQ_REL);
        }

        // ---- 3. issue h loads (one burst of 32 MALL loads; fly under x-MFMAs) ----
        const unsigned long long* hp = (const unsigned long long*)
            (hbuf + ((size_t)((d * 2 + p) * BB + b)) * HH);
        unsigned long long hl0[HF], hl1[HF];
        #pragma unroll
        for (int f = 0; f < HF; f++) {
            hl0[f] = __hip_atomic_load(hp + f * 8 + quad * 2,
                        __ATOMIC_RELAXED, __HIP_MEMORY_SCOPE_AGENT);
            hl1[f] = __hip_atomic_load(hp + f * 8 + quad * 2 + 1,
                        __ATOMIC_RELAXED, __HIP_MEMORY_SCOPE_AGENT);
        }
        __builtin_amdgcn_sched_barrier(0);   // pin h-load issue above x-MFMAs

        // ---- 4. x-projection MFMAs ----
        if constexpr (LAYER == 0) {
            #pragma unroll
            for (int f = 0; f < XF; f++) {
                uint4v r;
                r[0] = pack2bf(Fa[f].x, Fa[f].y); r[1] = pack2bf(Fa[f].z, Fa[f].w);
                r[2] = pack2bf(Fb[f].x, Fb[f].y); r[3] = pack2bf(Fb[f].z, Fb[f].w);
                acc = __builtin_amdgcn_mfma_f32_16x16x32_bf16(
                        __builtin_bit_cast(short8, Ar[f]),
                        __builtin_bit_cast(short8, r), acc, 0, 0, 0);
            }
        } else {
            #pragma unroll
            for (int f = 0; f < XF; f++)
                acc = __builtin_amdgcn_mfma_f32_16x16x32_bf16(
                        __builtin_bit_cast(short8, Ar[f]),
                        __builtin_bit_cast(short8, Bx[f]), acc, 0, 0, 0);
        }

        // ---- 5. h-recurrence MFMAs ----
        #pragma unroll
        for (int f = 0; f < HF; f++) {
            uint4v r;
            r[0] = (unsigned)hl0[f]; r[1] = (unsigned)(hl0[f] >> 32);
            r[2] = (unsigned)hl1[f]; r[3] = (unsigned)(hl1[f] >> 32);
            acc = __builtin_amdgcn_mfma_f32_16x16x32_bf16(
                    __builtin_bit_cast(short8, Ar[XF + f]),
                    __builtin_bit_cast(short8, r), acc, 0, 0, 0);
        }

        // ---- 6. epilogue: lane owns (batch b, unit u); acc[i] = gate i (i,f,g,o) ----
        float gi = acc[0] + bias_[0];
        float gf = acc[1] + bias_[1];
        float gg = acc[2] + bias_[2];
        float go = acc[3] + bias_[3];
        float i_ = 1.f / (1.f + __expf(-gi));
        float f_ = 1.f / (1.f + __expf(-gf));
        float xg = fminf(fmaxf(gg, -15.f), 15.f);
        float e2 = __expf(2.f * xg);
        float g_ = (e2 - 1.f) / (e2 + 1.f);
        float o_ = 1.f / (1.f + __expf(-go));
        c_ = f_ * c_ + i_ * g_;
        float xc  = fminf(fmaxf(c_, -15.f), 15.f);
        float e2c = __expf(2.f * xc);
        float hn  = o_ * ((e2c - 1.f) / (e2c + 1.f));

        // bf16 pair-pack (units u,u+1 via lane^16 partner), store by quads 0,2
        int hb = (int)f2bfu(hn);
        int ob = __shfl_xor(hb, 16);
        if (!(quad & 1)) {
            unsigned v32 = (unsigned)(unsigned short)hb
                         | ((unsigned)(unsigned short)ob << 16);
            __hip_atomic_store((unsigned*)(hbuf +
                ((size_t)((d * 2 + (p ^ 1)) * BB + b)) * HH + u),
                v32, __ATOMIC_RELAXED, __HIP_MEMORY_SCOPE_AGENT);
            if (LAYER == 0)
                *(unsigned*)(h0out + ((size_t)(b * SS + t)) * HD + d * HH + u) = v32;
        }
        if (LAYER == 1) {
            // fp8 4-pack (units jb*4..jb*4+3), one u32 store by quad 0
            __hip_fp8_e4m3 f8(hn);
            int b8  = (int)f8.__x;
            int o8  = __shfl_xor(b8, 16);
            int pr  = (b8 & 0xff) | ((o8 & 0xff) << 8);
            int pr2 = __shfl_xor(pr, 32);
            if (quad == 0) {
                unsigned val = (unsigned)(pr & 0xffff) | ((unsigned)(pr2 & 0xffff) << 16);
                // round-9 fix: restore the d*HH direction offset (round-8 bug:
                // both dirs clobbered cols 0..511, cols 512..1023 kept stale
                // packA0 bytes -> fp8 NaNs -> loss NaN)
                *(unsigned*)(h1out + ((size_t)(b * SS + t)) * HD + d * HH + jb * 4) = val;
            }
        }

        // ---- 7. arrive: drain own h stores to MALL, then publish flag ----
        asm volatile("s_waitcnt vmcnt(0)" ::: "memory");
        if (lane == 0)
            __hip_atomic_store(gflags + jb, (unsigned)(s + 1),
                               __ATOMIC_RELAXED, __HIP_MEMORY_SCOPE_AGENT);
    }
}

// ---------------------------------------------------------------------------
// logits[row,n] = sum_k fp8(h1[row,k]) * cls_w[n,k]   (cls_b added in CRF)
// 1 wave per row, 4 rows per block; Wc in LDS, conflict-free lane-consecutive.
// ---------------------------------------------------------------------------
__global__ __launch_bounds__(256)
void logits_fp8(const unsigned char* __restrict__ h1, const float* __restrict__ cls_w,
                float* __restrict__ out)
{
    __shared__ float Wc[TT * HD];
    const int tid = threadIdx.x;
    for (int i = tid; i < TT * HD; i += 256) Wc[i] = cls_w[i];
    __syncthreads();
    const int lane = tid & 63;
    const int row  = blockIdx.x * 4 + (tid >> 6);
    const unsigned char* xr = h1 + (size_t)row * HD;
    float p[TT] = {};
    #pragma unroll
    for (int it = 0; it < 16; it++) {
        __hip_fp8_e4m3 f8; f8.__x = xr[it * 64 + lane];
        float xv = (float)f8;
        #pragma unroll
        for (int n = 0; n < TT; n++) p[n] += xv * Wc[n * HD + it * 64 + lane];
    }
    #pragma unroll
    for (int n = 0; n < TT; n++) {
        float v = p[n];
        #pragma unroll
        for (int off = 32; off > 0; off >>= 1) v += __shfl_down(v, off);
        if (lane == 0) out[(size_t)row * TT + n] = v;
    }
}

// ---------------------------------------------------------------------------
// CRF viterbi + loss (validated rounds 2-6). cls_b folded here.
// ---------------------------------------------------------------------------
__global__ __launch_bounds__(64)
void crf_kernel(const float* __restrict__ logits, const int* __restrict__ labels,
                const int* __restrict__ vlens, const float* __restrict__ trans,
                const float* __restrict__ start_t, const float* __restrict__ end_t,
                const float* __restrict__ cls_b,
                float* __restrict__ tags_out, float* __restrict__ llh)
{
    const int b = blockIdx.x;
    const int lane = threadIdx.x;
    const int len = vlens[b];
    const float* em = logits + (size_t)b * (SS * TT);
    const int*  lab = labels + (size_t)b * SS;
    __shared__ unsigned char hist[(SS - 1) * TT];

    float cb = (lane < TT) ? cls_b[lane] : 0.f;
    float tcol[TT];
    #pragma unroll
    for (int i = 0; i < TT; i++) tcol[i] = (lane < TT) ? trans[i * TT + lane] : 0.f;
    float score = (lane < TT) ? (start_t[lane] + em[lane] + cb) : 0.f;
    float alpha = score;
    float num = 0.f; int plab = 0;
    if (lane == 0) { plab = lab[0]; num = start_t[plab] + em[plab] + cls_b[plab]; }

    for (int t = 1; t < SS; t++) {
        float emj = (lane < TT) ? (em[t * TT + lane] + cb) : 0.f;
        float sv[TT], av[TT];
        #pragma unroll
        for (int i = 0; i < TT; i++) { sv[i] = __shfl(score, i); av[i] = __shfl(alpha, i); }
        float best = -INFINITY; int bp = 0; float amx = -INFINITY;
        #pragma unroll
        for (int i = 0; i < TT; i++) {
            float cnd = sv[i] + tcol[i];
            if (cnd > best) { best = cnd; bp = i; }   // strict >: FIRST max
            amx = fmaxf(amx, av[i] + tcol[i]);
        }
        float se = 0.f;
        #pragma unroll
        for (int i = 0; i < TT; i++) se += expf(av[i] + tcol[i] - amx);
        const bool m = (t < len);
        if (m) { score = best + emj; alpha = amx + logf(se) + emj; }
        if (lane < TT) hist[(t - 1) * TT + lane] = (unsigned char)bp;
        if (lane == 0 && m) {
            int lt = lab[t];
            num += em[t * TT + lt] + cls_b[lt] + trans[plab * TT + lt];
            plab = lt;
        }
    }
    float fsc[TT], fal[TT];
    #pragma unroll
    for (int i = 0; i < TT; i++) { fsc[i] = __shfl(score, i); fal[i] = __shfl(alpha, i); }
    __syncthreads();
    if (lane == 0) {
        num += end_t[lab[len - 1]];
        int bl = 0; float bv = fsc[0] + end_t[0];
        #pragma unroll
        for (int i = 1; i < TT; i++) {
            float v = fsc[i] + end_t[i];
            if (v > bv) { bv = v; bl = i; }
        }
        float zmx = -INFINITY;
        #pragma unroll
        for (int i = 0; i < TT; i++) zmx = fmaxf(zmx, fal[i] + end_t[i]);
        float zse = 0.f;
        #pragma unroll
        for (int i = 0; i < TT; i++) zse += expf(fal[i] + end_t[i] - zmx);
        llh[b] = num - (zmx + logf(zse));
        int tag = bl;
        tags_out[b * SS + (SS - 1)] = (float)tag;
        for (int t = SS - 2; t >= 0; t--) {
            if (t + 1 < len) tag = hist[t * TT + tag];
            tags_out[b * SS + t] = (float)tag;
        }
    }
}

__global__ void loss_kernel(const float* __restrict__ llh, float* __restrict__ out)
{
    float v = llh[threadIdx.x];
    #pragma unroll
    for (int off = 32; off > 0; off >>= 1) v += __shfl_down(v, off);
    if (threadIdx.x == 0) out[MM] = -(v / 64.f);
}

// ---------------------------------------------------------------------------
extern "C" void kernel_launch(void* const* d_in, const int* in_sizes, int n_in,
                              void* d_out, int out_size, void* d_ws, size_t ws_size,
                              hipStream_t stream)
{
    const int*   ids     = (const int*)  d_in[0];
    const int*   vlen    = (const int*)  d_in[1];
    const int*   labels  = (const int*)  d_in[2];
    const float* emb     = (const float*)d_in[3];
    const float* w_ih0   = (const float*)d_in[4];
    const float* w_hh0   = (const float*)d_in[5];
    const float* b_ih0   = (const float*)d_in[6];
    const float* b_hh0   = (const float*)d_in[7];
    const float* w_ih1   = (const float*)d_in[8];
    const float* w_hh1   = (const float*)d_in[9];
    const float* b_ih1   = (const float*)d_in[10];
    const float* b_hh1   = (const float*)d_in[11];
    const float* cls_w   = (const float*)d_in[12];
    const float* cls_b   = (const float*)d_in[13];
    const float* trans   = (const float*)d_in[14];
    const float* start_t = (const float*)d_in[15];
    const float* end_t   = (const float*)d_in[16];

    // Workspace (~109 MB):
    // [llh 256B][flags 8KB][hbuf0 256KB][hbuf1 256KB][h0out 64MB bf16]
    // [packA1 12MB | logits 1.18MB after L1][packA0 6MB | h1out 32MB fp8 after L0]
    float*          llh    = (float*)d_ws;
    unsigned*       flags  = (unsigned*)(llh + 64);            // 2048 u32 (L0: 1024, L1: 1024)
    unsigned short* hbuf0  = (unsigned short*)(flags + 2048);
    unsigned short* hbuf1  = hbuf0 + 131072;
    unsigned short* h0out  = hbuf1 + 131072;                   // MM*HD bf16
    unsigned short* packA1 = h0out + (size_t)MM * HD;          // 6291456 shorts
    float*          logits = (float*)packA1;                   // overlay (post-L1)
    unsigned short* packA0 = packA1 + 6291456;                 // 3145728 shorts
    unsigned char*  h1out  = (unsigned char*)packA0;           // 32MB overlay (post-L0)

    // zero: flags (2048 u32) + hbuf0 + hbuf1 (contiguous)
    zero_kernel<<<512, 256, 0, stream>>>((float*)flags, 2048 + (131072 + 131072) / 2);

    pack_kernel<<<(3145728 + 255) / 256, 256, 0, stream>>>(w_ih0, w_hh0, packA0, EE, 24, 3145728);
    pack_kernel<<<(6291456 + 255) / 256, 256, 0, stream>>>(w_ih1, w_hh1, packA1, HD, 48, 6291456);

    bilstm_persist<0><<<256, 256, 0, stream>>>(
        ids, emb, nullptr, packA0, b_ih0, b_hh0, hbuf0, h0out, nullptr, flags);
    bilstm_persist<1><<<256, 256, 0, stream>>>(
        ids, nullptr, h0out, packA1, b_ih1, b_hh1, hbuf1, nullptr, h1out, flags + 1024);

    logits_fp8<<<MM / 4, 256, 0, stream>>>(h1out, cls_w, logits);
    crf_kernel<<<BB, 64, 0, stream>>>(logits, labels, vlen, trans, start_t, end_t,
                                      cls_b, (float*)d_out, llh);
    loss_kernel<<<1, 64, 0, stream>>>(llh, (float*)d_out);
}